// Round 6
// baseline (91.385 us; speedup 1.0000x reference)
//
#include <hip/hip_runtime.h>

// SimpleRNN: B=8192, T=1024, H=8.
// h_{t+1} = tanh(x_t*W_ih + b_ih + b_hh + h_t @ W_hh^T); out = sigmoid(h_T @ W_fc^T + b_fc)
// Layout: one batch per quad (4 lanes). Lane p (0..3) owns h[p] and h[p+4].
// Matvec via xor-systolic over r=0..3 (k = p^r) using DPP quad_perm (VALU-speed shuffles).

#define T_LEN 1024
#define DPP_XOR1 0xB1  // quad_perm(1,0,3,2)
#define DPP_XOR2 0x4E  // quad_perm(2,3,0,1)
#define DPP_XOR3 0x1B  // quad_perm(3,2,1,0)

template <int CTRL>
__device__ __forceinline__ float fdpp(float v) {
    int i = __builtin_bit_cast(int, v);
    int r = __builtin_amdgcn_mov_dpp(i, CTRL, 0xF, 0xF, true);
    return __builtin_bit_cast(float, r);
}

__device__ __forceinline__ float fast_tanh(float z) {
    // tanh(z) = 1 - 2/(exp(2z)+1); exp(2z) = 2^(z * 2/ln2)
    float e = __builtin_amdgcn_exp2f(z * 2.8853900817779268f);
    return 1.0f - 2.0f * __builtin_amdgcn_rcpf(e + 1.0f);
}

__device__ __forceinline__ float fast_sigmoid(float z) {
    float e = __builtin_amdgcn_exp2f(z * -1.4426950408889634f);
    return __builtin_amdgcn_rcpf(1.0f + e);
}

struct Wq {
    float wA[4], wB[4], wC[4], wD[4];
    float wih0, wih1, bias0, bias1;
};

__device__ __forceinline__ void step(float xt, float& h0, float& h1, const Wq& w) {
    // row p:   u0/v0 chains; row p+4: u1/v1 chains (2-way FMA trees)
    float u0 = __builtin_fmaf(h0, w.wA[0], __builtin_fmaf(xt, w.wih0, w.bias0));
    float v0 = h1 * w.wB[0];
    float u1 = __builtin_fmaf(h0, w.wC[0], __builtin_fmaf(xt, w.wih1, w.bias1));
    float v1 = h1 * w.wD[0];

    float a = fdpp<DPP_XOR1>(h0), c = fdpp<DPP_XOR1>(h1);
    u0 = __builtin_fmaf(a, w.wA[1], u0); v0 = __builtin_fmaf(c, w.wB[1], v0);
    u1 = __builtin_fmaf(a, w.wC[1], u1); v1 = __builtin_fmaf(c, w.wD[1], v1);

    a = fdpp<DPP_XOR2>(h0); c = fdpp<DPP_XOR2>(h1);
    u0 = __builtin_fmaf(a, w.wA[2], u0); v0 = __builtin_fmaf(c, w.wB[2], v0);
    u1 = __builtin_fmaf(a, w.wC[2], u1); v1 = __builtin_fmaf(c, w.wD[2], v1);

    a = fdpp<DPP_XOR3>(h0); c = fdpp<DPP_XOR3>(h1);
    u0 = __builtin_fmaf(a, w.wA[3], u0); v0 = __builtin_fmaf(c, w.wB[3], v0);
    u1 = __builtin_fmaf(a, w.wC[3], u1); v1 = __builtin_fmaf(c, w.wD[3], v1);

    h0 = fast_tanh(u0 + v0);
    h1 = fast_tanh(u1 + v1);
}

__global__ __launch_bounds__(64) void rnn_quad_kernel(
    const float* __restrict__ x, const float* __restrict__ W_ih,
    const float* __restrict__ W_hh, const float* __restrict__ b_ih,
    const float* __restrict__ b_hh, const float* __restrict__ W_fc,
    const float* __restrict__ b_fc, float* __restrict__ out, int B)
{
    const int tid = blockIdx.x * 64 + threadIdx.x;
    const int p = tid & 3;        // quad position -> owns h[p], h[p+4]
    const int b = tid >> 2;       // batch index
    if (b >= B) return;

    Wq w;
#pragma unroll
    for (int r = 0; r < 4; ++r) {
        const int k = p ^ r;
        w.wA[r] = W_hh[p * 8 + k];           // W_hh[p][k]
        w.wB[r] = W_hh[p * 8 + k + 4];       // W_hh[p][k+4]
        w.wC[r] = W_hh[(p + 4) * 8 + k];     // W_hh[p+4][k]
        w.wD[r] = W_hh[(p + 4) * 8 + k + 4]; // W_hh[p+4][k+4]
    }
    w.wih0 = W_ih[p];
    w.wih1 = W_ih[p + 4];
    w.bias0 = b_ih[p] + b_hh[p];
    w.bias1 = b_ih[p + 4] + b_hh[p + 4];
    const float wfc0 = W_fc[p], wfc1 = W_fc[p + 4];
    const float bfc = b_fc[0];

    const float* xb = x + (size_t)b * T_LEN;
    float h0 = 0.0f, h1 = 0.0f;

    // software pipeline: 8-step chunks (2x float4), prefetch 2 chunks ahead
    float4 cur0 = *(const float4*)(xb + 0);
    float4 cur1 = *(const float4*)(xb + 4);
    float4 nxt0 = *(const float4*)(xb + 8);
    float4 nxt1 = *(const float4*)(xb + 12);

#pragma unroll 1
    for (int t0 = 0; t0 < T_LEN; t0 += 8) {
        float4 pf0, pf1;
        const bool more = (t0 + 16) < T_LEN;
        if (more) {
            pf0 = *(const float4*)(xb + t0 + 16);
            pf1 = *(const float4*)(xb + t0 + 20);
        }
        step(cur0.x, h0, h1, w);
        step(cur0.y, h0, h1, w);
        step(cur0.z, h0, h1, w);
        step(cur0.w, h0, h1, w);
        step(cur1.x, h0, h1, w);
        step(cur1.y, h0, h1, w);
        step(cur1.z, h0, h1, w);
        step(cur1.w, h0, h1, w);
        cur0 = nxt0; cur1 = nxt1;
        if (more) { nxt0 = pf0; nxt1 = pf1; }
    }

    // final: out[b] = sigmoid(sum_j h[j]*W_fc[j] + b_fc); quad butterfly reduce
    float s = __builtin_fmaf(h0, wfc0, h1 * wfc1);
    s += fdpp<DPP_XOR1>(s);
    s += fdpp<DPP_XOR2>(s);
    if (p == 0) out[b] = fast_sigmoid(s + bfc);
}

extern "C" void kernel_launch(void* const* d_in, const int* in_sizes, int n_in,
                              void* d_out, int out_size, void* d_ws, size_t ws_size,
                              hipStream_t stream) {
    const float* x    = (const float*)d_in[0];
    const float* W_ih = (const float*)d_in[1];
    const float* W_hh = (const float*)d_in[2];
    const float* b_ih = (const float*)d_in[3];
    const float* b_hh = (const float*)d_in[4];
    const float* W_fc = (const float*)d_in[5];
    const float* b_fc = (const float*)d_in[6];
    float* out = (float*)d_out;

    const int B = in_sizes[0] / T_LEN;            // 8192
    const int threads = B * 4;                    // one quad per batch
    const int grid = (threads + 63) / 64;         // 64-thread blocks -> spread over CUs
    rnn_quad_kernel<<<grid, 64, 0, stream>>>(x, W_ih, W_hh, b_ih, b_hh, W_fc, b_fc, out, B);
}

// Round 7
// 87.367 us; speedup vs baseline: 1.0460x; 1.0460x over previous
//
#include <hip/hip_runtime.h>

// SimpleRNN: B=8192, T=1024, H=8.  h_{t+1} = tanh(pre_t + h_t @ W_hh^T); out = sigmoid(h@W_fc^T+b_fc)
// Quad-per-batch layout; lane p (0..3) owns h[p], h[p+4]. DPP quad_perm xor-systolic matvec.
// v2: weights pre-scaled by 2/ln2 so tanh = fma(-2, rcp(exp2(u)+1), 1)  [4-op chain tail];
//     input projection (x*wih+bias) hoisted off the recurrence chain (computed per 8-step chunk).

#define T_LEN 1024
#define DPP_XOR1 0xB1  // quad_perm(1,0,3,2)
#define DPP_XOR2 0x4E  // quad_perm(2,3,0,1)
#define DPP_XOR3 0x1B  // quad_perm(3,2,1,0)
#define TWO_OVER_LN2 2.8853900817779268f

template <int CTRL>
__device__ __forceinline__ float fdpp(float v) {
    int i = __builtin_bit_cast(int, v);
    int r = __builtin_amdgcn_mov_dpp(i, CTRL, 0xF, 0xF, true);
    return __builtin_bit_cast(float, r);
}

// u is pre-scaled by 2/ln2: tanh(z) = 1 - 2/(2^(z*2/ln2)+1)
__device__ __forceinline__ float tanh_scaled(float u) {
    float e = __builtin_amdgcn_exp2f(u);
    float r = __builtin_amdgcn_rcpf(e + 1.0f);
    return __builtin_fmaf(-2.0f, r, 1.0f);
}

__device__ __forceinline__ float fast_sigmoid(float z) {
    float e = __builtin_amdgcn_exp2f(z * -1.4426950408889634f);
    return __builtin_amdgcn_rcpf(1.0f + e);
}

struct Wq { float wA[4], wB[4], wC[4], wD[4]; };

// pre0/pre1 are (x*wih + bias) * 2/ln2, h-independent (off the chain).
__device__ __forceinline__ void step(float pre0, float pre1, float& h0, float& h1, const Wq& w) {
    float u0 = __builtin_fmaf(h0, w.wA[0], pre0);
    float v0 = h1 * w.wB[0];
    float u1 = __builtin_fmaf(h0, w.wC[0], pre1);
    float v1 = h1 * w.wD[0];

    float a = fdpp<DPP_XOR1>(h0), c = fdpp<DPP_XOR1>(h1);
    u0 = __builtin_fmaf(a, w.wA[1], u0); v0 = __builtin_fmaf(c, w.wB[1], v0);
    u1 = __builtin_fmaf(a, w.wC[1], u1); v1 = __builtin_fmaf(c, w.wD[1], v1);

    a = fdpp<DPP_XOR2>(h0); c = fdpp<DPP_XOR2>(h1);
    u0 = __builtin_fmaf(a, w.wA[2], u0); v0 = __builtin_fmaf(c, w.wB[2], v0);
    u1 = __builtin_fmaf(a, w.wC[2], u1); v1 = __builtin_fmaf(c, w.wD[2], v1);

    a = fdpp<DPP_XOR3>(h0); c = fdpp<DPP_XOR3>(h1);
    u0 = __builtin_fmaf(a, w.wA[3], u0); v0 = __builtin_fmaf(c, w.wB[3], v0);
    u1 = __builtin_fmaf(a, w.wC[3], u1); v1 = __builtin_fmaf(c, w.wD[3], v1);

    h0 = tanh_scaled(u0 + v0);
    h1 = tanh_scaled(u1 + v1);
}

__global__ __launch_bounds__(64) void rnn_quad_kernel(
    const float* __restrict__ x, const float* __restrict__ W_ih,
    const float* __restrict__ W_hh, const float* __restrict__ b_ih,
    const float* __restrict__ b_hh, const float* __restrict__ W_fc,
    const float* __restrict__ b_fc, float* __restrict__ out, int B)
{
    const int tid = blockIdx.x * 64 + threadIdx.x;
    const int p = tid & 3;
    const int b = tid >> 2;
    if (b >= B) return;

    Wq w;
#pragma unroll
    for (int r = 0; r < 4; ++r) {
        const int k = p ^ r;
        w.wA[r] = W_hh[p * 8 + k]           * TWO_OVER_LN2;
        w.wB[r] = W_hh[p * 8 + k + 4]       * TWO_OVER_LN2;
        w.wC[r] = W_hh[(p + 4) * 8 + k]     * TWO_OVER_LN2;
        w.wD[r] = W_hh[(p + 4) * 8 + k + 4] * TWO_OVER_LN2;
    }
    const float wih0  = W_ih[p]     * TWO_OVER_LN2;
    const float wih1  = W_ih[p + 4] * TWO_OVER_LN2;
    const float bias0 = (b_ih[p] + b_hh[p])         * TWO_OVER_LN2;
    const float bias1 = (b_ih[p + 4] + b_hh[p + 4]) * TWO_OVER_LN2;
    const float wfc0 = W_fc[p], wfc1 = W_fc[p + 4];
    const float bfc = b_fc[0];

    const float* xb = x + (size_t)b * T_LEN;
    float h0 = 0.0f, h1 = 0.0f;

    float4 cur0 = *(const float4*)(xb + 0);
    float4 cur1 = *(const float4*)(xb + 4);
    float4 nxt0 = *(const float4*)(xb + 8);
    float4 nxt1 = *(const float4*)(xb + 12);

#pragma unroll 1
    for (int t0 = 0; t0 < T_LEN; t0 += 8) {
        float4 pf0, pf1;
        const bool more = (t0 + 16) < T_LEN;
        if (more) {
            pf0 = *(const float4*)(xb + t0 + 16);
            pf1 = *(const float4*)(xb + t0 + 20);
        }
        // hoist input projection off the recurrence chain (h-independent ILP filler)
        float pa[8], pb[8];
        pa[0] = __builtin_fmaf(cur0.x, wih0, bias0); pb[0] = __builtin_fmaf(cur0.x, wih1, bias1);
        pa[1] = __builtin_fmaf(cur0.y, wih0, bias0); pb[1] = __builtin_fmaf(cur0.y, wih1, bias1);
        pa[2] = __builtin_fmaf(cur0.z, wih0, bias0); pb[2] = __builtin_fmaf(cur0.z, wih1, bias1);
        pa[3] = __builtin_fmaf(cur0.w, wih0, bias0); pb[3] = __builtin_fmaf(cur0.w, wih1, bias1);
        pa[4] = __builtin_fmaf(cur1.x, wih0, bias0); pb[4] = __builtin_fmaf(cur1.x, wih1, bias1);
        pa[5] = __builtin_fmaf(cur1.y, wih0, bias0); pb[5] = __builtin_fmaf(cur1.y, wih1, bias1);
        pa[6] = __builtin_fmaf(cur1.z, wih0, bias0); pb[6] = __builtin_fmaf(cur1.z, wih1, bias1);
        pa[7] = __builtin_fmaf(cur1.w, wih0, bias0); pb[7] = __builtin_fmaf(cur1.w, wih1, bias1);

#pragma unroll
        for (int i = 0; i < 8; ++i)
            step(pa[i], pb[i], h0, h1, w);

        cur0 = nxt0; cur1 = nxt1;
        if (more) { nxt0 = pf0; nxt1 = pf1; }
    }

    float s = __builtin_fmaf(h0, wfc0, h1 * wfc1);
    s += fdpp<DPP_XOR1>(s);
    s += fdpp<DPP_XOR2>(s);
    if (p == 0) out[b] = fast_sigmoid(s + bfc);
}

extern "C" void kernel_launch(void* const* d_in, const int* in_sizes, int n_in,
                              void* d_out, int out_size, void* d_ws, size_t ws_size,
                              hipStream_t stream) {
    const float* x    = (const float*)d_in[0];
    const float* W_ih = (const float*)d_in[1];
    const float* W_hh = (const float*)d_in[2];
    const float* b_ih = (const float*)d_in[3];
    const float* b_hh = (const float*)d_in[4];
    const float* W_fc = (const float*)d_in[5];
    const float* b_fc = (const float*)d_in[6];
    float* out = (float*)d_out;

    const int B = in_sizes[0] / T_LEN;            // 8192
    const int threads = B * 4;
    const int grid = (threads + 63) / 64;
    rnn_quad_kernel<<<grid, 64, 0, stream>>>(x, W_ih, W_hh, b_ih, b_hh, W_fc, b_fc, out, B);
}